// Round 17
// baseline (147.694 us; speedup 1.0000x reference)
//
#include <hip/hip_runtime.h>
#include <stdint.h>

#define Bsz 16384
#define Hh  512
#define Kd  1024      // I + H
#define BM  256       // M rows per workgroup
#define NT  32        // K tiles of 32

// LDS buffer: A 16KB + B 10KB = 26KB; three buffers = 78KB
#define BUFB 26624

typedef __attribute__((ext_vector_type(8))) short bf16x8;
typedef __attribute__((ext_vector_type(4))) float f32x4;
typedef __attribute__((ext_vector_type(8))) unsigned short u16x8;

__device__ __forceinline__ unsigned short f2bf(float f) {
    union { float f; unsigned u; } v; v.f = f;
    unsigned u = v.u;
    return (unsigned short)((u + 0x7fffu + ((u >> 16) & 1u)) >> 16);
}
__device__ __forceinline__ float fast_tanh(float x) {
    float e = __expf(2.f * x);
    return (e - 1.f) / (e + 1.f);
}
__device__ __forceinline__ float fast_sigmoid(float x) {
    return 1.f / (1.f + __expf(-x));
}

// ---- pack A fragment-linear (R12-proven): unit blk = (mblk*32 + t)*8 + u ----
// elem blk*512 + l*8 + e = A[mblk*128 + u*16 + (l&15)][t*32 + (l>>4)*8 + e]
__global__ void pack_A(const float* __restrict__ x, const float* __restrict__ h,
                       unsigned short* __restrict__ A) {
    const long total = (long)Bsz * Kd / 8;   // 2,097,152 units of 8
    for (long i = (long)blockIdx.x * blockDim.x + threadIdx.x; i < total;
         i += (long)gridDim.x * blockDim.x) {
        int  l    = (int)(i & 63);
        long blk  = i >> 6;
        int  u    = (int)(blk & 7);
        int  t    = (int)((blk >> 3) & 31);
        long mblk = blk >> 8;
        long row  = mblk * 128 + u * 16 + (l & 15);
        int  k0   = t * 32 + ((l >> 4) << 3);
        const float* src = (k0 < 512) ? (x + row * 512 + k0)
                                      : (h + row * 512 + (k0 - 512));
        float4 f0 = *(const float4*)(src);
        float4 f1 = *(const float4*)(src + 4);
        u16x8 o;
        o[0]=f2bf(f0.x); o[1]=f2bf(f0.y); o[2]=f2bf(f0.z); o[3]=f2bf(f0.w);
        o[4]=f2bf(f1.x); o[5]=f2bf(f1.y); o[6]=f2bf(f1.z); o[7]=f2bf(f1.w);
        *(u16x8*)(A + (i << 3)) = o;
    }
}

// ---- pack B fragment-linear (proven): ----
// elem jgrp*81920 + g*16384 + t32*512 + l*8 + e
//  = W[g][ j = jgrp*16 + (l&15) ][ k = t32*32 + (l>>4)*8 + e ]
__global__ void pack_B(const float* __restrict__ Wxi, const float* __restrict__ Whi,
                       const float* __restrict__ Wxf, const float* __restrict__ Whf,
                       const float* __restrict__ Wxc, const float* __restrict__ Whc,
                       const float* __restrict__ Wxo, const float* __restrict__ Who,
                       const float* __restrict__ We,
                       const float* __restrict__ bxi, const float* __restrict__ bhi,
                       const float* __restrict__ bxf, const float* __restrict__ bhf,
                       const float* __restrict__ bxc, const float* __restrict__ bhc,
                       const float* __restrict__ bxo, const float* __restrict__ bho,
                       const float* __restrict__ be,
                       unsigned short* __restrict__ Bp, float* __restrict__ bias) {
    const long id = (long)blockIdx.x * blockDim.x + threadIdx.x;  // 327680 total
    if (id < 327680) {
        int blk = (int)(id >> 6);
        int l   = (int)(id & 63);
        int kh  = blk & 1;
        int kt  = (blk >> 1) & 15;
        int rest = blk >> 5;
        int g    = rest % 5;
        int jgrp = rest / 5;
        int j  = jgrp * 16 + (l & 15);
        int k0 = kt * 64 + kh * 32 + ((l >> 4) << 3);
        const float* src;
        if (g == 4) {
            src = We + (long)j * 1024 + k0;
        } else {
            const float* Wx = (g == 0) ? Wxi : (g == 1) ? Wxf : (g == 2) ? Wxc : Wxo;
            const float* Wh = (g == 0) ? Whi : (g == 1) ? Whf : (g == 2) ? Whc : Who;
            src = (k0 < 512) ? (Wx + (long)j * 512 + k0)
                             : (Wh + (long)j * 512 + (k0 - 512));
        }
        float4 f0 = *(const float4*)(src);
        float4 f1 = *(const float4*)(src + 4);
        u16x8 o;
        o[0]=f2bf(f0.x); o[1]=f2bf(f0.y); o[2]=f2bf(f0.z); o[3]=f2bf(f0.w);
        o[4]=f2bf(f1.x); o[5]=f2bf(f1.y); o[6]=f2bf(f1.z); o[7]=f2bf(f1.w);
        *(u16x8*)(Bp + (long)blk * 512 + l * 8) = o;
    }
    if (id < 2560) {
        int row = (int)id;
        int g = row >> 9, j = row & 511;
        float b;
        if (g == 4) b = be[j];
        else {
            const float* bx = (g == 0) ? bxi : (g == 1) ? bxf : (g == 2) ? bxc : bxo;
            const float* bh = (g == 0) ? bhi : (g == 1) ? bhf : (g == 2) ? bhc : bho;
            b = bx[j] + bh[j];
        }
        bias[row] = b;
    }
}

// ---- fused GEMM: 1 wave/SIMD, wave = 128M x (16j x 5 gates), acc 160, 40-MFMA clusters ----
#define GL16(g, l) __builtin_amdgcn_global_load_lds( \
    (const __attribute__((address_space(1))) unsigned int*)(g), \
    (__attribute__((address_space(3))) unsigned int*)(l), 16, 0, 0)

#define VM_I(n)    asm volatile("s_waitcnt vmcnt(" #n ")" ::: "memory")
#define VM(n)      VM_I(n)
#define BARRIER()  asm volatile("s_barrier" ::: "memory")

#define MF(a, b, c) __builtin_amdgcn_mfma_f32_16x16x32_bf16(a, b, c, 0, 0, 0)

// read all 13 fragments of tile in buffer at byte BO (plain loads -> compiler lgkm)
#define RDALL(BO) do { \
    _Pragma("unroll") \
    for (int m_ = 0; m_ < 8; ++m_) \
        af[m_] = *(const bf16x8*)(aRP + (BO) + m_ * 1024); \
    _Pragma("unroll") \
    for (int g_ = 0; g_ < 5; ++g_) \
        bq[g_] = *(const bf16x8*)(bRP + (BO) + g_ * 1024); \
} while (0)

#define MFMA40() do { \
    __builtin_amdgcn_s_setprio(1); \
    _Pragma("unroll") \
    for (int g_ = 0; g_ < 5; ++g_) \
        _Pragma("unroll") \
        for (int m_ = 0; m_ < 8; ++m_) \
            acc[m_][g_] = MF(af[m_], bq[g_], acc[m_][g_]); \
    __builtin_amdgcn_s_setprio(0); \
} while (0)

// stage tile T into buffer at byte SO: 7 GL16 per thread (28 units, 2 benign dups)
#define SG7(SO, T) do { \
    GL16(sg0 + (long)(T) * st0, lds_raw + (SO) + ld0); \
    GL16(sg1 + (long)(T) * st1, lds_raw + (SO) + ld1); \
    GL16(sg2 + (long)(T) * st2, lds_raw + (SO) + ld2); \
    GL16(sg3 + (long)(T) * st3, lds_raw + (SO) + ld3); \
    GL16(sg4 + (long)(T) * st4, lds_raw + (SO) + ld4); \
    GL16(sg5 + (long)(T) * st5, lds_raw + (SO) + ld5); \
    GL16(sg6 + (long)(T) * st6, lds_raw + (SO) + ld6); \
} while (0)

// one K32-tile: read 13 frags, stage T+2, 40 MFMA, counted vmcnt, 1 barrier
#define TILE(T, RBO, SBO, STG, WN, SYNC) do { \
    RDALL(RBO); \
    if (STG) SG7(SBO, (T) + 2); \
    MFMA40(); \
    if (SYNC) { VM(WN); BARRIER(); } \
} while (0)

__global__ __launch_bounds__(256, 1)
void xlstm_gemm(const unsigned short* __restrict__ Apk,
                const unsigned short* __restrict__ Bp,
                const float* __restrict__ bias,
                const float* __restrict__ c_prev,
                float* __restrict__ out) {
    __shared__ __align__(16) unsigned char lds_raw[3 * BUFB];  // 78 KB

    const int tid  = threadIdx.x;
    const int wid  = tid >> 6;
    const int lane = tid & 63;
    const int wm   = wid >> 1;    // 0..1 : 128-row half
    const int wj   = wid & 1;     // 0..1 : 16-j group
    const int fr   = lane & 15;
    const int q    = lane >> 4;

    // T1: bijective XCD swizzle (nwg = 1024, 1024 % 8 == 0)
    const int orig = blockIdx.x;
    const int wg   = (orig & 7) * 128 + (orig >> 3);
    const int Mblk = wg >> 4;     // 0..63
    const int Jblk = wg & 15;     // 0..15
    const long brow = (long)Mblk * BM;

    f32x4 acc[8][5];
#pragma unroll
    for (int m = 0; m < 8; ++m)
#pragma unroll
        for (int g = 0; g < 5; ++g)
#pragma unroll
            for (int r = 0; r < 4; ++r) acc[m][g][r] = 0.f;

    bf16x8 af[8];
    bf16x8 bq[5];

    // ---- read-side LDS pointers ----
    // A units (wm*8+m) at (wm*8+m)*1024; B units (wj*5+g) at 16384 + (wj*5+g)*1024
    const unsigned char* aRP = lds_raw + wm * 8192 + lane * 16;
    const unsigned char* bRP = lds_raw + 16384 + wj * 5120 + lane * 16;

    // ---- staging slots: 7 per thread; unit u = s*4 + wid (28 slots, >=26 wrap) ----
    const unsigned short *sg0, *sg1, *sg2, *sg3, *sg4, *sg5, *sg6;
    int st0, st1, st2, st3, st4, st5, st6;
    int ld0, ld1, ld2, ld3, ld4, ld5, ld6;
#define SLOT_INIT(s) do { \
    int u_ = (s) * 4 + wid; if (u_ >= 26) u_ -= 26; \
    if (u_ < 16) { \
        long mb_ = (long)(Mblk * 2 + (u_ >> 3)); \
        sg##s = Apk + mb_ * 131072 + (u_ & 7) * 512 + lane * 8; \
        st##s = 4096; \
    } else { \
        int b_ = u_ - 16; int wjg_ = b_ / 5; int g_ = b_ - 5 * wjg_; \
        sg##s = Bp + (long)(Jblk * 2 + wjg_) * 81920 + g_ * 16384 + lane * 8; \
        st##s = 512; \
    } \
    ld##s = u_ * 1024 + lane * 16; \
} while (0)
    SLOT_INIT(0); SLOT_INIT(1); SLOT_INIT(2); SLOT_INIT(3);
    SLOT_INIT(4); SLOT_INIT(5); SLOT_INIT(6);
#undef SLOT_INIT

    // ---- prologue: stage tiles 0,1 -> bufs 0,1; certify tile 0 ----
    SG7(0, 0);
    SG7(BUFB, 1);
    VM(7);           // tile 0's 7 done; tile 1's 7 in flight
    BARRIER();

    // ---- main loop: tile t reads buf t%3, stages t+2 into buf (t+2)%3 ----
    for (int t = 0; t < 30; t += 3) {
        TILE(t,     0 * BUFB, 2 * BUFB, 1, 7, 1);
        TILE(t + 1, 1 * BUFB, 0 * BUFB, 1, 7, 1);
        TILE(t + 2, 2 * BUFB, 1 * BUFB, 1, 7, 1);
    }
    // loop staged up to tile 31 (t=29 staged 31); drain and finish
    TILE(30, 0 * BUFB, 0, 0, 0, 1);   // VM(0): certify tile 31
    TILE(31, 1 * BUFB, 0, 0, 0, 0);

    // ---------------- epilogue (fused, in-register) ----------------
    const int j = Jblk * 32 + wj * 16 + fr;
    const float bi_ = bias[j];
    const float bf_ = bias[512 + j];
    const float bc_ = bias[1024 + j];
    const float bo_ = bias[1536 + j];
    const float be_ = bias[2048 + j];
    const long mbase = brow + wm * 128 + (q << 2);
#pragma unroll
    for (int m = 0; m < 8; ++m) {
#pragma unroll
        for (int r = 0; r < 4; ++r) {
            long row = mbase + m * 16 + r;
            float gi = acc[m][0][r] + bi_;
            float gf = acc[m][1][r] + bf_;
            float gc = acc[m][2][r] + bc_;
            float go = acc[m][3][r] + bo_;
            float ge = acc[m][4][r] + be_;
            float iv = fast_sigmoid(gi);
            float fv = fast_sigmoid(gf);
            float gv = fast_tanh(gc);
            float ov = fast_sigmoid(go);
            float ef = __expf(fast_tanh(ge));
            float cp = c_prev[row * 512 + j];
            float cv = fv * cp + iv * gv;
            float hv = ov * fast_tanh(cv) * ef;
            out[row * 512 + j] = hv;
            out[(long)Bsz * 512 + row * 512 + j] = cv;
        }
    }
}

extern "C" void kernel_launch(void* const* d_in, const int* in_sizes, int n_in,
                              void* d_out, int out_size, void* d_ws, size_t ws_size,
                              hipStream_t stream) {
    const float* x      = (const float*)d_in[0];
    const float* h_prev = (const float*)d_in[1];
    const float* c_prev = (const float*)d_in[2];
    const float* Wxi = (const float*)d_in[3];
    const float* bxi = (const float*)d_in[4];
    const float* Whi = (const float*)d_in[5];
    const float* bhi = (const float*)d_in[6];
    const float* Wxf = (const float*)d_in[7];
    const float* bxf = (const float*)d_in[8];
    const float* Whf = (const float*)d_in[9];
    const float* bhf = (const float*)d_in[10];
    const float* Wxc = (const float*)d_in[11];
    const float* bxc = (const float*)d_in[12];
    const float* Whc = (const float*)d_in[13];
    const float* bhc = (const float*)d_in[14];
    const float* Wxo = (const float*)d_in[15];
    const float* bxo = (const float*)d_in[16];
    const float* Who = (const float*)d_in[17];
    const float* bho = (const float*)d_in[18];
    const float* We  = (const float*)d_in[19];
    const float* be  = (const float*)d_in[20];

    unsigned short* Abf  = (unsigned short*)d_ws;                        // 33,554,432 B
    unsigned short* Bp   = (unsigned short*)((char*)d_ws + 33554432);    //  5,242,880 B
    float*          bias = (float*)((char*)d_ws + 33554432 + 5242880);   //     10,240 B

    pack_A<<<2048, 256, 0, stream>>>(x, h_prev, Abf);
    pack_B<<<1280, 256, 0, stream>>>(Wxi, Whi, Wxf, Whf, Wxc, Whc, Wxo, Who, We,
                                     bxi, bhi, bxf, bhf, bxc, bhc, bxo, bho, be,
                                     Bp, bias);
    xlstm_gemm<<<1024, 256, 0, stream>>>(Abf, Bp, bias, c_prev, (float*)d_out);
}

// Round 18
// 121.567 us; speedup vs baseline: 1.2149x; 1.2149x over previous
//
#include <hip/hip_runtime.h>
#include <stdint.h>

#define Bsz 16384
#define Hh  512
#define Kd  1024      // I + H
#define BM  256       // M rows per workgroup
#define BNJ 32        // j columns per workgroup (x5 gates)
#define NT  32        // K tiles of 32

// LDS buffer: A 16KB + B 10KB = 26KB; three buffers = 78KB (1 wg/CU by VGPR anyway)
#define BUFB 26624

typedef __attribute__((ext_vector_type(8))) short bf16x8;
typedef __attribute__((ext_vector_type(4))) float f32x4;
typedef __attribute__((ext_vector_type(8))) unsigned short u16x8;

__device__ __forceinline__ unsigned short f2bf(float f) {
    union { float f; unsigned u; } v; v.f = f;
    unsigned u = v.u;
    return (unsigned short)((u + 0x7fffu + ((u >> 16) & 1u)) >> 16);
}
__device__ __forceinline__ float fast_tanh(float x) {
    float e = __expf(2.f * x);
    return (e - 1.f) / (e + 1.f);
}
__device__ __forceinline__ float fast_sigmoid(float x) {
    return 1.f / (1.f + __expf(-x));
}

// ---- pack A fragment-linear (R12/R17-proven): unit blk = (mblk*32 + t)*8 + u ----
// elem blk*512 + l*8 + e = A[mblk*128 + u*16 + (l&15)][t*32 + (l>>4)*8 + e]
__global__ void pack_A(const float* __restrict__ x, const float* __restrict__ h,
                       unsigned short* __restrict__ A) {
    const long total = (long)Bsz * Kd / 8;   // 2,097,152 units of 8
    for (long i = (long)blockIdx.x * blockDim.x + threadIdx.x; i < total;
         i += (long)gridDim.x * blockDim.x) {
        int  l    = (int)(i & 63);
        long blk  = i >> 6;
        int  u    = (int)(blk & 7);
        int  t    = (int)((blk >> 3) & 31);
        long mblk = blk >> 8;
        long row  = mblk * 128 + u * 16 + (l & 15);
        int  k0   = t * 32 + ((l >> 4) << 3);
        const float* src = (k0 < 512) ? (x + row * 512 + k0)
                                      : (h + row * 512 + (k0 - 512));
        float4 f0 = *(const float4*)(src);
        float4 f1 = *(const float4*)(src + 4);
        u16x8 o;
        o[0]=f2bf(f0.x); o[1]=f2bf(f0.y); o[2]=f2bf(f0.z); o[3]=f2bf(f0.w);
        o[4]=f2bf(f1.x); o[5]=f2bf(f1.y); o[6]=f2bf(f1.z); o[7]=f2bf(f1.w);
        *(u16x8*)(A + (i << 3)) = o;
    }
}

// ---- pack B fragment-linear (proven): ----
// elem jgrp*81920 + g*16384 + t32*512 + l*8 + e
//  = W[g][ j = jgrp*16 + (l&15) ][ k = t32*32 + (l>>4)*8 + e ]
__global__ void pack_B(const float* __restrict__ Wxi, const float* __restrict__ Whi,
                       const float* __restrict__ Wxf, const float* __restrict__ Whf,
                       const float* __restrict__ Wxc, const float* __restrict__ Whc,
                       const float* __restrict__ Wxo, const float* __restrict__ Who,
                       const float* __restrict__ We,
                       const float* __restrict__ bxi, const float* __restrict__ bhi,
                       const float* __restrict__ bxf, const float* __restrict__ bhf,
                       const float* __restrict__ bxc, const float* __restrict__ bhc,
                       const float* __restrict__ bxo, const float* __restrict__ bho,
                       const float* __restrict__ be,
                       unsigned short* __restrict__ Bp, float* __restrict__ bias) {
    const long id = (long)blockIdx.x * blockDim.x + threadIdx.x;  // 327680 total
    if (id < 327680) {
        int blk = (int)(id >> 6);
        int l   = (int)(id & 63);
        int kh  = blk & 1;
        int kt  = (blk >> 1) & 15;
        int rest = blk >> 5;
        int g    = rest % 5;
        int jgrp = rest / 5;
        int j  = jgrp * 16 + (l & 15);
        int k0 = kt * 64 + kh * 32 + ((l >> 4) << 3);
        const float* src;
        if (g == 4) {
            src = We + (long)j * 1024 + k0;
        } else {
            const float* Wx = (g == 0) ? Wxi : (g == 1) ? Wxf : (g == 2) ? Wxc : Wxo;
            const float* Wh = (g == 0) ? Whi : (g == 1) ? Whf : (g == 2) ? Whc : Who;
            src = (k0 < 512) ? (Wx + (long)j * 512 + k0)
                             : (Wh + (long)j * 512 + (k0 - 512));
        }
        float4 f0 = *(const float4*)(src);
        float4 f1 = *(const float4*)(src + 4);
        u16x8 o;
        o[0]=f2bf(f0.x); o[1]=f2bf(f0.y); o[2]=f2bf(f0.z); o[3]=f2bf(f0.w);
        o[4]=f2bf(f1.x); o[5]=f2bf(f1.y); o[6]=f2bf(f1.z); o[7]=f2bf(f1.w);
        *(u16x8*)(Bp + (long)blk * 512 + l * 8) = o;
    }
    if (id < 2560) {
        int row = (int)id;
        int g = row >> 9, j = row & 511;
        float b;
        if (g == 4) b = be[j];
        else {
            const float* bx = (g == 0) ? bxi : (g == 1) ? bxf : (g == 2) ? bxc : bxo;
            const float* bh = (g == 0) ? bhi : (g == 1) ? bhf : (g == 2) ? bhc : bho;
            b = bx[j] + bh[j];
        }
        bias[row] = b;
    }
}

// ---- fused GEMM: 16 waves (4/SIMD), acc 40, 3 bufs depth-2, counted vmcnt ----
#define GL16(g, l) __builtin_amdgcn_global_load_lds( \
    (const __attribute__((address_space(1))) unsigned int*)(g), \
    (__attribute__((address_space(3))) unsigned int*)(l), 16, 0, 0)

#define VM_I(n)    asm volatile("s_waitcnt vmcnt(" #n ")" ::: "memory")
#define VM(n)      VM_I(n)
#define BARRIER()  asm volatile("s_barrier" ::: "memory")

#define MF(a, b, c) __builtin_amdgcn_mfma_f32_16x16x32_bf16(a, b, c, 0, 0, 0)

// read the wave's 7 fragments from buffer at byte BO (compiler inserts lgkm waits)
#define RD7(BO) do { \
    af0 = *(const bf16x8*)(aRP + (BO) + 0 * 1024); \
    af1 = *(const bf16x8*)(aRP + (BO) + 1 * 1024); \
    bq0 = *(const bf16x8*)(bRP + (BO) + 0 * 1024); \
    bq1 = *(const bf16x8*)(bRP + (BO) + 1 * 1024); \
    bq2 = *(const bf16x8*)(bRP + (BO) + 2 * 1024); \
    bq3 = *(const bf16x8*)(bRP + (BO) + 3 * 1024); \
    bq4 = *(const bf16x8*)(bRP + (BO) + 4 * 1024); \
} while (0)

#define MFMA10() do { \
    __builtin_amdgcn_s_setprio(1); \
    acc[0][0] = MF(af0, bq0, acc[0][0]); acc[0][1] = MF(af1, bq0, acc[0][1]); \
    acc[1][0] = MF(af0, bq1, acc[1][0]); acc[1][1] = MF(af1, bq1, acc[1][1]); \
    acc[2][0] = MF(af0, bq2, acc[2][0]); acc[2][1] = MF(af1, bq2, acc[2][1]); \
    acc[3][0] = MF(af0, bq3, acc[3][0]); acc[3][1] = MF(af1, bq3, acc[3][1]); \
    acc[4][0] = MF(af0, bq4, acc[4][0]); acc[4][1] = MF(af1, bq4, acc[4][1]); \
    __builtin_amdgcn_s_setprio(0); \
} while (0)

// stage tile T into buffer at byte SO: 2 GL16 per wave (uniform)
#define SG2(SO, T) do { \
    GL16(sg0 + (long)(T) * st0, lds_raw + (SO) + ld0); \
    GL16(sg1 + (long)(T) * st1, lds_raw + (SO) + ld1); \
} while (0)

// one K32-tile
#define TILE(T, RBO, SBO, STG, WN, SYNC) do { \
    RD7(RBO); \
    if (STG) SG2(SBO, (T) + 2); \
    MFMA10(); \
    if (SYNC) { VM(WN); BARRIER(); } \
} while (0)

__global__ __launch_bounds__(1024, 1)
void xlstm_gemm(const unsigned short* __restrict__ Apk,
                const unsigned short* __restrict__ Bp,
                const float* __restrict__ bias,
                const float* __restrict__ c_prev,
                float* __restrict__ out) {
    __shared__ __align__(16) unsigned char lds_raw[3 * BUFB];  // 78 KB

    const int tid  = threadIdx.x;
    const int wid  = tid >> 6;    // 0..15
    const int lane = tid & 63;
    const int wm   = wid >> 1;    // 0..7 : 32-row group
    const int wj   = wid & 1;     // 0..1 : 16-j group
    const int fr   = lane & 15;
    const int q    = lane >> 4;

    // T1: bijective XCD swizzle (nwg = 1024, 1024 % 8 == 0)
    const int orig = blockIdx.x;
    const int wg   = (orig & 7) * 128 + (orig >> 3);
    const int Mblk = wg >> 4;     // 0..63
    const int Jblk = wg & 15;     // 0..15
    const long brow = (long)Mblk * BM;

    f32x4 acc[5][2];
#pragma unroll
    for (int g = 0; g < 5; ++g)
#pragma unroll
        for (int m = 0; m < 2; ++m)
#pragma unroll
            for (int r = 0; r < 4; ++r) acc[g][m][r] = 0.f;

    bf16x8 af0, af1, bq0, bq1, bq2, bq3, bq4;

    // ---- read-side LDS pointers ----
    // A unit (wm*2+m) at (wm*2+m)*1024; B unit (wj*5+g) at 16384 + (wj*5+g)*1024
    const unsigned char* aRP = lds_raw + wm * 2048 + lane * 16;
    const unsigned char* bRP = lds_raw + 16384 + wj * 5120 + lane * 16;

    // ---- staging slots: 2 per wave; unit u = wid*2 + s, wrap >=26 (benign dups) ----
    const unsigned short *sg0, *sg1;
    int st0, st1, ld0, ld1;
#define SLOT_INIT(s) do { \
    int u_ = wid * 2 + (s); if (u_ >= 26) u_ -= 26; \
    if (u_ < 16) { \
        long mb_ = (long)(Mblk * 2 + (u_ >> 3)); \
        sg##s = Apk + mb_ * 131072 + (u_ & 7) * 512 + lane * 8; \
        st##s = 4096; \
    } else { \
        int b_ = u_ - 16; int jg_ = b_ / 5; int g_ = b_ - 5 * jg_; \
        sg##s = Bp + (long)(Jblk * 2 + jg_) * 81920 + g_ * 16384 + lane * 8; \
        st##s = 512; \
    } \
    ld##s = u_ * 1024 + lane * 16; \
} while (0)
    SLOT_INIT(0); SLOT_INIT(1);
#undef SLOT_INIT

    // ---- prologue: stage tiles 0,1 -> bufs 0,1; certify tile 0 ----
    SG2(0, 0);
    SG2(BUFB, 1);
    VM(2);           // tile 0's 2 done; tile 1's 2 in flight
    BARRIER();

    // ---- main loop: tile t reads buf t%3, stages t+2 into buf (t+2)%3 ----
    for (int t = 0; t < 30; t += 3) {
        TILE(t,     0 * BUFB, 2 * BUFB, 1, 2, 1);
        TILE(t + 1, 1 * BUFB, 0 * BUFB, 1, 2, 1);
        TILE(t + 2, 2 * BUFB, 1 * BUFB, 1, 2, 1);
    }
    // staged through tile 31 (t=29 staged it into buf1)
    TILE(30, 0 * BUFB, 0, 0, 0, 1);   // VM(0): certify tile 31
    TILE(31, 1 * BUFB, 0, 0, 0, 0);

    // ---------------- epilogue (fused, in-register) ----------------
    const int j = Jblk * 32 + wj * 16 + fr;
    const float bi_ = bias[j];
    const float bf_ = bias[512 + j];
    const float bc_ = bias[1024 + j];
    const float bo_ = bias[1536 + j];
    const float be_ = bias[2048 + j];
    const long mbase = brow + wm * 32 + (q << 2);
#pragma unroll
    for (int m = 0; m < 2; ++m) {
#pragma unroll
        for (int r = 0; r < 4; ++r) {
            long row = mbase + m * 16 + r;
            float gi = acc[0][m][r] + bi_;
            float gf = acc[1][m][r] + bf_;
            float gc = acc[2][m][r] + bc_;
            float go = acc[3][m][r] + bo_;
            float ge = acc[4][m][r] + be_;
            float iv = fast_sigmoid(gi);
            float fv = fast_sigmoid(gf);
            float gv = fast_tanh(gc);
            float ov = fast_sigmoid(go);
            float ef = __expf(fast_tanh(ge));
            float cp = c_prev[row * 512 + j];
            float cv = fv * cp + iv * gv;
            float hv = ov * fast_tanh(cv) * ef;
            out[row * 512 + j] = hv;
            out[(long)Bsz * 512 + row * 512 + j] = cv;
        }
    }
}

extern "C" void kernel_launch(void* const* d_in, const int* in_sizes, int n_in,
                              void* d_out, int out_size, void* d_ws, size_t ws_size,
                              hipStream_t stream) {
    const float* x      = (const float*)d_in[0];
    const float* h_prev = (const float*)d_in[1];
    const float* c_prev = (const float*)d_in[2];
    const float* Wxi = (const float*)d_in[3];
    const float* bxi = (const float*)d_in[4];
    const float* Whi = (const float*)d_in[5];
    const float* bhi = (const float*)d_in[6];
    const float* Wxf = (const float*)d_in[7];
    const float* bxf = (const float*)d_in[8];
    const float* Whf = (const float*)d_in[9];
    const float* bhf = (const float*)d_in[10];
    const float* Wxc = (const float*)d_in[11];
    const float* bxc = (const float*)d_in[12];
    const float* Whc = (const float*)d_in[13];
    const float* bhc = (const float*)d_in[14];
    const float* Wxo = (const float*)d_in[15];
    const float* bxo = (const float*)d_in[16];
    const float* Who = (const float*)d_in[17];
    const float* bho = (const float*)d_in[18];
    const float* We  = (const float*)d_in[19];
    const float* be  = (const float*)d_in[20];

    unsigned short* Abf  = (unsigned short*)d_ws;                        // 33,554,432 B
    unsigned short* Bp   = (unsigned short*)((char*)d_ws + 33554432);    //  5,242,880 B
    float*          bias = (float*)((char*)d_ws + 33554432 + 5242880);   //     10,240 B

    pack_A<<<2048, 256, 0, stream>>>(x, h_prev, Abf);
    pack_B<<<1280, 256, 0, stream>>>(Wxi, Whi, Wxf, Whf, Wxc, Whc, Wxo, Who, We,
                                     bxi, bhi, bxf, bhf, bxc, bhc, bxo, bho, be,
                                     Bp, bias);
    xlstm_gemm<<<1024, 1024, 0, stream>>>(Abf, Bp, bias, c_prev, (float*)d_out);
}